// Round 1
// baseline (1800.239 us; speedup 1.0000x reference)
//
#include <hip/hip_runtime.h>

// 2-layer GRU (B=512, T=4096, H=3) + linear decoder, fully fused.
// One thread per batch element; all weights in registers, gates via
// prescaled exp2/rcp. Serial over T (inherent), parallel over B.

constexpr int T = 4096;
constexpr int B = 512;
constexpr float LOG2E = 1.44269504088896340736f;

__device__ __forceinline__ float fexp2(float v) { return __builtin_amdgcn_exp2f(v); }
__device__ __forceinline__ float frcp(float v)  { return __builtin_amdgcn_rcpf(v); }

__global__ __launch_bounds__(64, 1)
void gru_fused(const float* __restrict__ x,     // [B,T,3]
               const float* __restrict__ h0,    // [2,B,3]
               const float* __restrict__ Wih,   // [2,9,3]
               const float* __restrict__ Whh,   // [2,9,3]
               const float* __restrict__ bih,   // [2,9]
               const float* __restrict__ bhh,   // [2,9]
               const float* __restrict__ Wdec,  // [1,3]
               const float* __restrict__ bdec,  // [1]
               float* __restrict__ out)         // y[B*T] then h_out[2*B*3]
{
    const int b = blockIdx.x * 64 + threadIdx.x;
    if (b >= B) return;

    // ---- Load weights into registers, pre-scaled so that:
    //   r/z gates: chain value = -log2(e) * (gi + gh)  -> sig = rcp(1+exp2(chain))
    //   n gate:    chain value = 2*log2(e) * (gi_n + r*gh_n) -> tanh = 1 - 2*rcp(1+exp2(chain))
    float wi[2][9][3], wh[2][9][3], bsum[2][6], bin[2][3], bhn[2][3];
    #pragma unroll
    for (int l = 0; l < 2; ++l) {
        #pragma unroll
        for (int g = 0; g < 9; ++g) {
            const float sc = (g < 6) ? -LOG2E : (2.0f * LOG2E);
            #pragma unroll
            for (int k = 0; k < 3; ++k) {
                wi[l][g][k] = Wih[(l * 9 + g) * 3 + k] * sc;
                wh[l][g][k] = Whh[(l * 9 + g) * 3 + k] * sc;
            }
            if (g < 6) {
                bsum[l][g] = (bih[l * 9 + g] + bhh[l * 9 + g]) * sc;  // r,z: biases combine
            } else {
                bin[l][g - 6] = bih[l * 9 + g] * sc;   // n: keep separate (r scales gh_n)
                bhn[l][g - 6] = bhh[l * 9 + g] * sc;
            }
        }
    }
    const float wd0 = Wdec[0], wd1 = Wdec[1], wd2 = Wdec[2], bd = bdec[0];

    float h[2][3];
    #pragma unroll
    for (int l = 0; l < 2; ++l)
        #pragma unroll
        for (int k = 0; k < 3; ++k)
            h[l][k] = h0[l * B * 3 + b * 3 + k];

    const float4* xb = reinterpret_cast<const float4*>(x + (size_t)b * T * 3);
    float4*       yb = reinterpret_cast<float4*>(out + (size_t)b * T);

    float4 c0 = xb[0], c1 = xb[1], c2 = xb[2];

    #pragma unroll 1
    for (int tc = 0; tc < T / 4; ++tc) {
        // software prefetch next chunk (masked index stays in-bounds; last iter re-reads chunk 0)
        const int nidx = ((tc + 1) & (T / 4 - 1)) * 3;
        const float4 n0 = xb[nidx], n1 = xb[nidx + 1], n2 = xb[nidx + 2];

        const float xs[4][3] = {
            {c0.x, c0.y, c0.z},
            {c0.w, c1.x, c1.y},
            {c1.z, c1.w, c2.x},
            {c2.y, c2.z, c2.w},
        };
        float yv[4];
        #pragma unroll
        for (int s = 0; s < 4; ++s) {
            float in0 = xs[s][0], in1 = xs[s][1], in2 = xs[s][2];
            #pragma unroll
            for (int l = 0; l < 2; ++l) {
                const float hl0 = h[l][0], hl1 = h[l][1], hl2 = h[l][2];
                float hn[3];
                #pragma unroll
                for (int j = 0; j < 3; ++j) {
                    float cr = bsum[l][j];
                    cr = fmaf(wi[l][j][0], in0, cr);
                    cr = fmaf(wi[l][j][1], in1, cr);
                    cr = fmaf(wi[l][j][2], in2, cr);
                    cr = fmaf(wh[l][j][0], hl0, cr);
                    cr = fmaf(wh[l][j][1], hl1, cr);
                    cr = fmaf(wh[l][j][2], hl2, cr);

                    float cz = bsum[l][3 + j];
                    cz = fmaf(wi[l][3 + j][0], in0, cz);
                    cz = fmaf(wi[l][3 + j][1], in1, cz);
                    cz = fmaf(wi[l][3 + j][2], in2, cz);
                    cz = fmaf(wh[l][3 + j][0], hl0, cz);
                    cz = fmaf(wh[l][3 + j][1], hl1, cz);
                    cz = fmaf(wh[l][3 + j][2], hl2, cz);

                    float gin = bin[l][j];
                    gin = fmaf(wi[l][6 + j][0], in0, gin);
                    gin = fmaf(wi[l][6 + j][1], in1, gin);
                    gin = fmaf(wi[l][6 + j][2], in2, gin);

                    float ghn = bhn[l][j];
                    ghn = fmaf(wh[l][6 + j][0], hl0, ghn);
                    ghn = fmaf(wh[l][6 + j][1], hl1, ghn);
                    ghn = fmaf(wh[l][6 + j][2], hl2, ghn);

                    const float r = frcp(1.0f + fexp2(cr));
                    const float z = frcp(1.0f + fexp2(cz));
                    const float en = fexp2(fmaf(r, ghn, gin));
                    const float n = fmaf(-2.0f, frcp(1.0f + en), 1.0f);
                    hn[j] = fmaf(z, h[l][j] - n, n);   // (1-z)*n + z*h
                }
                h[l][0] = hn[0]; h[l][1] = hn[1]; h[l][2] = hn[2];
                in0 = hn[0]; in1 = hn[1]; in2 = hn[2];  // layer-1 input / decoder input
            }
            yv[s] = fmaf(wd2, in2, fmaf(wd1, in1, fmaf(wd0, in0, bd)));
        }
        float4 y4;
        y4.x = yv[0]; y4.y = yv[1]; y4.z = yv[2]; y4.w = yv[3];
        yb[tc] = y4;
        c0 = n0; c1 = n1; c2 = n2;
    }

    // final hidden states: out[B*T + (l*B + b)*3 + k]
    #pragma unroll
    for (int l = 0; l < 2; ++l)
        #pragma unroll
        for (int k = 0; k < 3; ++k)
            out[B * T + (l * B + b) * 3 + k] = h[l][k];
}

extern "C" void kernel_launch(void* const* d_in, const int* in_sizes, int n_in,
                              void* d_out, int out_size, void* d_ws, size_t ws_size,
                              hipStream_t stream) {
    const float* x    = (const float*)d_in[0];
    const float* h0   = (const float*)d_in[1];
    const float* Wih  = (const float*)d_in[2];
    const float* Whh  = (const float*)d_in[3];
    const float* bih  = (const float*)d_in[4];
    const float* bhh  = (const float*)d_in[5];
    const float* Wdec = (const float*)d_in[6];
    const float* bdec = (const float*)d_in[7];
    float* out = (float*)d_out;

    gru_fused<<<B / 64, 64, 0, stream>>>(x, h0, Wih, Whh, bih, bhh, Wdec, bdec, out);
}

// Round 3
// 509.596 us; speedup vs baseline: 3.5327x; 3.5327x over previous
//
#include <hip/hip_runtime.h>

// 2-layer GRU (B=512, T=4096, H=3) + decoder, lane-parallel + layer-pipelined.
//
// 8 lanes per batch element:
//   lanes 0-2 (quad 0): layer-0 hidden units j=0..2   lane 3: dummy
//   lanes 4-6 (quad 1): layer-1 hidden units j=0..2   lane 7: dummy + y-store
// Uniform instruction stream: each lane runs "one GRU unit-gate step" with its
// own per-lane weights. Layer 1 processes step t-1 while layer 0 processes
// step t (software pipeline across quads); hand-off via DPP row_shr:4 of the
// per-quad h broadcasts (quad_perm). Decoder y lags 2 iterations.

constexpr int T = 4096;
constexpr int B = 512;
constexpr float LOG2E = 1.44269504088896340736f;

__device__ __forceinline__ float fexp2(float v) { return __builtin_amdgcn_exp2f(v); }
__device__ __forceinline__ float frcp(float v)  { return __builtin_amdgcn_rcpf(v); }

template<int CTRL>
__device__ __forceinline__ float dppf(float v) {
    return __int_as_float(
        __builtin_amdgcn_update_dpp(0, __float_as_int(v), CTRL, 0xF, 0xF, true));
}
// quad_perm broadcast of lane k within quad: ctrl = k * 0x55
// row_shr:4 : ctrl = 0x114  (lane n <- lane n-4; row-edge lanes get 0, discarded)

// One pipeline iteration. MODE: 0 = normal, 1 = first (freeze quad-1 h),
// 2 = last (freeze quad-0 h). Produces y for step (i-2) (valid on q1 lanes).
#define GRU_IT(MODE, X0, X1, X2, YV) do {                                      \
    float hb0 = dppf<0x00>(h), hb1 = dppf<0x55>(h), hb2 = dppf<0xAA>(h);       \
    YV = fmaf(wd2, hb2, fmaf(wd1, hb1, fmaf(wd0, hb0, bd)));                   \
    float s0 = dppf<0x114>(hb0), s1 = dppf<0x114>(hb1), s2 = dppf<0x114>(hb2); \
    float in0 = is_q0 ? (X0) : s0;                                             \
    float in1 = is_q0 ? (X1) : s1;                                             \
    float in2 = is_q0 ? (X2) : s2;                                             \
    float cr = br;                                                             \
    cr = fmaf(wir0, in0, cr); cr = fmaf(wir1, in1, cr); cr = fmaf(wir2, in2, cr); \
    cr = fmaf(whr0, hb0, cr); cr = fmaf(whr1, hb1, cr); cr = fmaf(whr2, hb2, cr); \
    float cz = bz;                                                             \
    cz = fmaf(wiz0, in0, cz); cz = fmaf(wiz1, in1, cz); cz = fmaf(wiz2, in2, cz); \
    cz = fmaf(whz0, hb0, cz); cz = fmaf(whz1, hb1, cz); cz = fmaf(whz2, hb2, cz); \
    float gi = bni;                                                            \
    gi = fmaf(win0, in0, gi); gi = fmaf(win1, in1, gi); gi = fmaf(win2, in2, gi); \
    float gh = bnh;                                                            \
    gh = fmaf(whn0, hb0, gh); gh = fmaf(whn1, hb1, gh); gh = fmaf(whn2, hb2, gh); \
    float r  = frcp(1.0f + fexp2(cr));                                         \
    float zz = frcp(1.0f + fexp2(cz));                                         \
    float nn = fmaf(-2.0f, frcp(1.0f + fexp2(fmaf(r, gh, gi))), 1.0f);         \
    float hn = fmaf(zz, h - nn, nn);                                           \
    if ((MODE) == 0)      h = hn;                                              \
    else if ((MODE) == 1) h = is_q0 ? hn : h;                                  \
    else                  h = is_q0 ? h : hn;                                  \
} while (0)

__global__ __launch_bounds__(64, 1)
void gru_pipe(const float* __restrict__ x,     // [B,T,3]
              const float* __restrict__ h0,    // [2,B,3]
              const float* __restrict__ Wih,   // [2,9,3]
              const float* __restrict__ Whh,   // [2,9,3]
              const float* __restrict__ bih,   // [2,9]
              const float* __restrict__ bhh,   // [2,9]
              const float* __restrict__ Wdec,  // [1,3]
              const float* __restrict__ bdec,  // [1]
              float* __restrict__ out)         // y[B*T] then h_out[2*B*3]
{
    const int lane  = threadIdx.x;           // 0..63, block = 1 wave
    const int g8    = lane & 7;              // position within 8-lane group
    const int layer = (g8 >> 2) & 1;         // quad parity = layer
    const int jj    = g8 & 3;
    const int j     = jj > 2 ? 2 : jj;       // clamped row (dummy lanes reuse j=2)
    const bool dummy = (jj == 3);
    const bool is_q0 = (layer == 0);
    const int b = (blockIdx.x * 64 + lane) >> 3;   // batch element

    // ---- per-lane weights, pre-scaled:
    //   r/z chains carry -log2(e); n chains carry 2*log2(e)
    const float zm = dummy ? 0.0f : 1.0f;    // dummy lanes: all-zero params (no NaN)
    const float sR = -LOG2E * zm, sN = 2.0f * LOG2E * zm;
    const float* Wi = Wih + layer * 27;
    const float* Wh = Whh + layer * 27;
    const float* bi = bih + layer * 9;
    const float* bh = bhh + layer * 9;

    const float wir0 = Wi[j*3+0]*sR, wir1 = Wi[j*3+1]*sR, wir2 = Wi[j*3+2]*sR;
    const float wiz0 = Wi[(3+j)*3+0]*sR, wiz1 = Wi[(3+j)*3+1]*sR, wiz2 = Wi[(3+j)*3+2]*sR;
    const float win0 = Wi[(6+j)*3+0]*sN, win1 = Wi[(6+j)*3+1]*sN, win2 = Wi[(6+j)*3+2]*sN;
    const float whr0 = Wh[j*3+0]*sR, whr1 = Wh[j*3+1]*sR, whr2 = Wh[j*3+2]*sR;
    const float whz0 = Wh[(3+j)*3+0]*sR, whz1 = Wh[(3+j)*3+1]*sR, whz2 = Wh[(3+j)*3+2]*sR;
    const float whn0 = Wh[(6+j)*3+0]*sN, whn1 = Wh[(6+j)*3+1]*sN, whn2 = Wh[(6+j)*3+2]*sN;
    const float br  = (bi[j] + bh[j]) * sR;
    const float bz  = (bi[3+j] + bh[3+j]) * sR;
    const float bni = bi[6+j] * sN;
    const float bnh = bh[6+j] * sN;
    const float wd0 = Wdec[0], wd1 = Wdec[1], wd2 = Wdec[2], bd = bdec[0];

    float h = dummy ? 0.0f : h0[layer * B * 3 + b * 3 + j];

    const float4* xb = reinterpret_cast<const float4*>(x + (size_t)b * T * 3);
    float* yo = out + (size_t)b * T;

    float4 c0 = xb[0], c1 = xb[1], c2 = xb[2];
    float y0, y1, y2, y3;

    // ---- chunk 0 (prologue: freeze layer-1 h at i=0) ----
    {
        float4 n0 = xb[3], n1 = xb[4], n2 = xb[5];
        GRU_IT(1, c0.x, c0.y, c0.z, y0);   // i=0
        GRU_IT(0, c0.w, c1.x, c1.y, y1);   // i=1
        GRU_IT(0, c1.z, c1.w, c2.x, y2);   // i=2 -> y(0)
        GRU_IT(0, c2.y, c2.z, c2.w, y3);   // i=3 -> y(1)
        if (g8 == 7) { float2 p; p.x = y2; p.y = y3; *(float2*)yo = p; }
        c0 = n0; c1 = n1; c2 = n2;
    }

    // ---- main loop: chunks 1..1023 ----
    #pragma unroll 1
    for (int tc = 1; tc < T / 4; ++tc) {
        const int nidx = ((tc + 1) & (T / 4 - 1)) * 3;   // masked prefetch
        float4 n0 = xb[nidx], n1 = xb[nidx + 1], n2 = xb[nidx + 2];
        GRU_IT(0, c0.x, c0.y, c0.z, y0);   // i=4tc   -> y(4tc-2)
        GRU_IT(0, c0.w, c1.x, c1.y, y1);   //         -> y(4tc-1)
        GRU_IT(0, c1.z, c1.w, c2.x, y2);   //         -> y(4tc)
        GRU_IT(0, c2.y, c2.z, c2.w, y3);   //         -> y(4tc+1)
        if (g8 == 7) {
            float2 pa, pb;
            pa.x = y0; pa.y = y1; pb.x = y2; pb.y = y3;
            *(float2*)(yo + 4 * tc - 2) = pa;
            *(float2*)(yo + 4 * tc)     = pb;
        }
        c0 = n0; c1 = n1; c2 = n2;
    }

    // ---- epilogue ----
    GRU_IT(2, 0.0f, 0.0f, 0.0f, y0);       // i=T: layer-1 finishes h1(T-1); y(T-2)
    {
        float hb0 = dppf<0x00>(h), hb1 = dppf<0x55>(h), hb2 = dppf<0xAA>(h);
        y1 = fmaf(wd2, hb2, fmaf(wd1, hb1, fmaf(wd0, hb0, bd)));   // y(T-1)
    }
    if (g8 == 7) { float2 p; p.x = y0; p.y = y1; *(float2*)(yo + T - 2) = p; }

    // final hidden states
    if (!dummy) out[B * T + (layer * B + b) * 3 + j] = h;
}

extern "C" void kernel_launch(void* const* d_in, const int* in_sizes, int n_in,
                              void* d_out, int out_size, void* d_ws, size_t ws_size,
                              hipStream_t stream) {
    const float* x    = (const float*)d_in[0];
    const float* h0   = (const float*)d_in[1];
    const float* Wih  = (const float*)d_in[2];
    const float* Whh  = (const float*)d_in[3];
    const float* bih  = (const float*)d_in[4];
    const float* bhh  = (const float*)d_in[5];
    const float* Wdec = (const float*)d_in[6];
    const float* bdec = (const float*)d_in[7];
    float* out = (float*)d_out;

    gru_pipe<<<(B * 8) / 64, 64, 0, stream>>>(x, h0, Wih, Whh, bih, bhh,
                                              Wdec, bdec, out);
}

// Round 4
// 493.536 us; speedup vs baseline: 3.6476x; 1.0325x over previous
//
#include <hip/hip_runtime.h>

// 2-layer GRU (B=512, T=4096, H=3) + decoder, lane-parallel + layer-pipelined
// + packed-fp32 gate math (v_pk_fma_f32).
//
// 8 lanes per batch element:
//   lanes 0-2 (quad 0): layer-0 hidden units j=0..2   lane 3: dummy
//   lanes 4-6 (quad 1): layer-1 hidden units j=0..2   lane 7: dummy + y-store
// Layer 1 processes step t-1 while layer 0 processes step t (pipeline across
// quads); hand-off via DPP row_shr:4 of the quad_perm h broadcasts.
// Gate chains packed in pairs: {r,z} and {n_h, decoder} -> v_pk_fma_f32.

constexpr int T = 4096;
constexpr int B = 512;
constexpr float LOG2E = 1.44269504088896340736f;

typedef float v2f __attribute__((ext_vector_type(2)));

__device__ __forceinline__ float fexp2(float v) { return __builtin_amdgcn_exp2f(v); }
__device__ __forceinline__ float frcp(float v)  { return __builtin_amdgcn_rcpf(v); }
__device__ __forceinline__ v2f vfma(v2f a, v2f b, v2f c) {
    return __builtin_elementwise_fma(a, b, c);   // llvm.fma.v2f32 -> v_pk_fma_f32
}
__device__ __forceinline__ v2f sp(float x) { v2f r; r.x = x; r.y = x; return r; }

template<int CTRL>
__device__ __forceinline__ float dppf(float v) {
    return __int_as_float(
        __builtin_amdgcn_update_dpp(0, __float_as_int(v), CTRL, 0xF, 0xF, true));
}
// quad_perm broadcast of lane k within quad: ctrl = k * 0x55
// row_shr:4 : ctrl = 0x114 (lane n <- lane n-4; quad0 lanes get 0, discarded)

// One pipeline iteration. MODE: 0 = normal, 1 = first (freeze quad-1 h),
// 2 = last (freeze quad-0 h). YV = y(i-2), valid on quad-1 lanes.
#define GRU_IT(MODE, X0, X1, X2, YV) do {                                      \
    float hb0 = dppf<0x00>(h), hb1 = dppf<0x55>(h), hb2 = dppf<0xAA>(h);       \
    float s0 = dppf<0x114>(hb0), s1 = dppf<0x114>(hb1), s2 = dppf<0x114>(hb2); \
    float in0 = is_q0 ? (X0) : s0;                                             \
    float in1 = is_q0 ? (X1) : s1;                                             \
    float in2 = is_q0 ? (X2) : s2;                                             \
    v2f arz = vfma(wirz0, sp(in0), brz);        /* x-side subchain */          \
    arz = vfma(wirz1, sp(in1), arz);                                           \
    arz = vfma(wirz2, sp(in2), arz);                                           \
    v2f hrz = vfma(whrz1, sp(hb1), whrz0 * sp(hb0));  /* h-side subchain */    \
    hrz = vfma(whrz2, sp(hb2), hrz);                                           \
    v2f crz = arz + hrz;                                                       \
    float r  = frcp(1.0f + fexp2(crz.x));                                      \
    float zz = frcp(1.0f + fexp2(crz.y));                                      \
    v2f cnd = vfma(wnd1, sp(hb1), vfma(wnd0, sp(hb0), bnd)); /* {gh, dec} */   \
    cnd = vfma(wnd2, sp(hb2), cnd);                                            \
    YV = cnd.y;                                                                \
    float gi = fmaf(win1, in1, fmaf(win0, in0, bni));                          \
    gi = fmaf(win2, in2, gi);                                                  \
    float nn = fmaf(-2.0f, frcp(1.0f + fexp2(fmaf(r, cnd.x, gi))), 1.0f);      \
    float omz = 1.0f - zz;                                                     \
    float zh  = zz * h;                                                        \
    float hn  = fmaf(omz, nn, zh);              /* (1-z)*n + z*h */            \
    if ((MODE) == 0)      h = hn;                                              \
    else if ((MODE) == 1) h = is_q0 ? hn : h;                                  \
    else                  h = is_q0 ? h : hn;                                  \
} while (0)

__global__ __launch_bounds__(64, 1)
void gru_pipe(const float* __restrict__ x,     // [B,T,3]
              const float* __restrict__ h0,    // [2,B,3]
              const float* __restrict__ Wih,   // [2,9,3]
              const float* __restrict__ Whh,   // [2,9,3]
              const float* __restrict__ bih,   // [2,9]
              const float* __restrict__ bhh,   // [2,9]
              const float* __restrict__ Wdec,  // [1,3]
              const float* __restrict__ bdec,  // [1]
              float* __restrict__ out)         // y[B*T] then h_out[2*B*3]
{
    const int lane  = threadIdx.x;           // 0..63, block = 1 wave
    const int g8    = lane & 7;              // position within 8-lane group
    const int layer = (g8 >> 2) & 1;         // quad parity = layer
    const int jj    = g8 & 3;
    const int j     = jj > 2 ? 2 : jj;       // clamped row (dummy lanes reuse j=2)
    const bool dummy = (jj == 3);
    const bool is_q0 = (layer == 0);
    const int b = (blockIdx.x * 64 + lane) >> 3;   // batch element

    // ---- per-lane weights, pre-scaled:
    //   r/z chains carry -log2(e); n chains carry 2*log2(e); dummy lanes zeroed
    const float zm = dummy ? 0.0f : 1.0f;
    const float sR = -LOG2E * zm, sN = 2.0f * LOG2E * zm;
    const float* Wi = Wih + layer * 27;
    const float* Wh = Whh + layer * 27;
    const float* bi = bih + layer * 9;
    const float* bh = bhh + layer * 9;

    v2f wirz0, wirz1, wirz2, whrz0, whrz1, whrz2, brz;
    wirz0.x = Wi[j*3+0]*sR;     wirz0.y = Wi[(3+j)*3+0]*sR;
    wirz1.x = Wi[j*3+1]*sR;     wirz1.y = Wi[(3+j)*3+1]*sR;
    wirz2.x = Wi[j*3+2]*sR;     wirz2.y = Wi[(3+j)*3+2]*sR;
    whrz0.x = Wh[j*3+0]*sR;     whrz0.y = Wh[(3+j)*3+0]*sR;
    whrz1.x = Wh[j*3+1]*sR;     whrz1.y = Wh[(3+j)*3+1]*sR;
    whrz2.x = Wh[j*3+2]*sR;     whrz2.y = Wh[(3+j)*3+2]*sR;
    brz.x   = (bi[j] + bh[j]) * sR;
    brz.y   = (bi[3+j] + bh[3+j]) * sR;

    const float wd0 = Wdec[0], wd1 = Wdec[1], wd2 = Wdec[2], bd = bdec[0];
    v2f wnd0, wnd1, wnd2, bnd;                     // {whn_k, wd_k}, {bnh, bd}
    wnd0.x = Wh[(6+j)*3+0]*sN;  wnd0.y = wd0;
    wnd1.x = Wh[(6+j)*3+1]*sN;  wnd1.y = wd1;
    wnd2.x = Wh[(6+j)*3+2]*sN;  wnd2.y = wd2;
    bnd.x  = bh[6+j]*sN;        bnd.y  = bd;

    const float win0 = Wi[(6+j)*3+0]*sN, win1 = Wi[(6+j)*3+1]*sN,
                win2 = Wi[(6+j)*3+2]*sN;
    const float bni  = bi[6+j]*sN;

    float h = dummy ? 0.0f : h0[layer * B * 3 + b * 3 + j];

    const float4* xb = reinterpret_cast<const float4*>(x + (size_t)b * T * 3);
    float* yo = out + (size_t)b * T;

    float4 c0 = xb[0], c1 = xb[1], c2 = xb[2];
    float y0, y1, y2, y3;

    // ---- chunk 0 (prologue: freeze layer-1 h at i=0) ----
    {
        float4 n0 = xb[3], n1 = xb[4], n2 = xb[5];
        GRU_IT(1, c0.x, c0.y, c0.z, y0);   // i=0
        GRU_IT(0, c0.w, c1.x, c1.y, y1);   // i=1
        GRU_IT(0, c1.z, c1.w, c2.x, y2);   // i=2 -> y(0)
        GRU_IT(0, c2.y, c2.z, c2.w, y3);   // i=3 -> y(1)
        if (g8 == 7) { float2 p; p.x = y2; p.y = y3; *(float2*)yo = p; }
        c0 = n0; c1 = n1; c2 = n2;
    }

    // ---- main loop: chunks 1..1023 ----
    #pragma unroll 1
    for (int tc = 1; tc < T / 4; ++tc) {
        const int nidx = ((tc + 1) & (T / 4 - 1)) * 3;   // masked prefetch
        float4 n0 = xb[nidx], n1 = xb[nidx + 1], n2 = xb[nidx + 2];
        GRU_IT(0, c0.x, c0.y, c0.z, y0);   // i=4tc   -> y(4tc-2)
        GRU_IT(0, c0.w, c1.x, c1.y, y1);   //         -> y(4tc-1)
        GRU_IT(0, c1.z, c1.w, c2.x, y2);   //         -> y(4tc)
        GRU_IT(0, c2.y, c2.z, c2.w, y3);   //         -> y(4tc+1)
        if (g8 == 7) {
            float2 pa, pb;
            pa.x = y0; pa.y = y1; pb.x = y2; pb.y = y3;
            *(float2*)(yo + 4 * tc - 2) = pa;
            *(float2*)(yo + 4 * tc)     = pb;
        }
        c0 = n0; c1 = n1; c2 = n2;
    }

    // ---- epilogue ----
    GRU_IT(2, 0.0f, 0.0f, 0.0f, y0);       // i=T: layer-1 finishes h1(T-1); y(T-2)
    {
        float hb0 = dppf<0x00>(h), hb1 = dppf<0x55>(h), hb2 = dppf<0xAA>(h);
        y1 = fmaf(wd2, hb2, fmaf(wd1, hb1, fmaf(wd0, hb0, bd)));   // y(T-1)
    }
    if (g8 == 7) { float2 p; p.x = y0; p.y = y1; *(float2*)(yo + T - 2) = p; }

    // final hidden states
    if (!dummy) out[B * T + (layer * B + b) * 3 + j] = h;
}

extern "C" void kernel_launch(void* const* d_in, const int* in_sizes, int n_in,
                              void* d_out, int out_size, void* d_ws, size_t ws_size,
                              hipStream_t stream) {
    const float* x    = (const float*)d_in[0];
    const float* h0   = (const float*)d_in[1];
    const float* Wih  = (const float*)d_in[2];
    const float* Whh  = (const float*)d_in[3];
    const float* bih  = (const float*)d_in[4];
    const float* bhh  = (const float*)d_in[5];
    const float* Wdec = (const float*)d_in[6];
    const float* bdec = (const float*)d_in[7];
    float* out = (float*)d_out;

    gru_pipe<<<(B * 8) / 64, 64, 0, stream>>>(x, h0, Wih, Whh, bih, bhh,
                                              Wdec, bdec, out);
}

// Round 6
// 481.607 us; speedup vs baseline: 3.7380x; 1.0248x over previous
//
#include <hip/hip_runtime.h>

// 2-layer GRU (B=512, T=4096, H=3) + decoder, lane-parallel + layer-pipelined
// + packed-fp32 gate math + distance-2 prefetch + aligned float4 y-stores.
//
// 8 lanes per batch element:
//   lanes 0-2 (quad 0): layer-0 hidden units j=0..2   lane 3: dummy
//   lanes 4-6 (quad 1): layer-1 hidden units j=0..2   lane 7: dummy + y-store
// Layer 1 processes step t-1 while layer 0 processes step t (pipeline across
// quads); hand-off via DPP row_shr:4 of the quad_perm h broadcasts.
// Gate chains packed in pairs: {r,z} and {n_h, decoder} -> v_pk_fma_f32.

constexpr int T = 4096;
constexpr int B = 512;
constexpr float LOG2E = 1.44269504088896340736f;

typedef float v2f __attribute__((ext_vector_type(2)));

__device__ __forceinline__ float fexp2(float v) { return __builtin_amdgcn_exp2f(v); }
__device__ __forceinline__ float frcp(float v)  { return __builtin_amdgcn_rcpf(v); }
__device__ __forceinline__ v2f vfma(v2f a, v2f b, v2f c) {
    return __builtin_elementwise_fma(a, b, c);   // llvm.fma.v2f32 -> v_pk_fma_f32
}
__device__ __forceinline__ v2f sp(float x) { v2f r; r.x = x; r.y = x; return r; }

template<int CTRL>
__device__ __forceinline__ float dppf(float v) {
    return __int_as_float(
        __builtin_amdgcn_update_dpp(0, __float_as_int(v), CTRL, 0xF, 0xF, true));
}
// quad_perm broadcast of lane k within quad: ctrl = k * 0x55
// row_shr:4 : ctrl = 0x114 (lane n <- lane n-4; quad0 lanes' s discarded)

// One pipeline iteration. MODE: 0 = normal, 1 = first (freeze quad-1 h),
// 2 = last (freeze quad-0 h). YV = y(i-2), valid on quad-1 lanes.
#define GRU_IT(MODE, X0, X1, X2, YV) do {                                      \
    float hb0 = dppf<0x00>(h), hb1 = dppf<0x55>(h), hb2 = dppf<0xAA>(h);       \
    float s0 = dppf<0x114>(hb0), s1 = dppf<0x114>(hb1), s2 = dppf<0x114>(hb2); \
    float in0 = is_q0 ? (X0) : s0;                                             \
    float in1 = is_q0 ? (X1) : s1;                                             \
    float in2 = is_q0 ? (X2) : s2;                                             \
    v2f arz = vfma(wirz0, sp(in0), brz);        /* x-side subchain */          \
    arz = vfma(wirz1, sp(in1), arz);                                           \
    arz = vfma(wirz2, sp(in2), arz);                                           \
    v2f hrz = vfma(whrz1, sp(hb1), whrz0 * sp(hb0));  /* h-side subchain */    \
    hrz = vfma(whrz2, sp(hb2), hrz);                                           \
    v2f crz = arz + hrz;                                                       \
    float r  = frcp(1.0f + fexp2(crz.x));                                      \
    float zz = frcp(1.0f + fexp2(crz.y));                                      \
    v2f cnd = vfma(wnd1, sp(hb1), vfma(wnd0, sp(hb0), bnd)); /* {gh, dec} */   \
    cnd = vfma(wnd2, sp(hb2), cnd);                                            \
    YV = cnd.y;                                                                \
    float gi = fmaf(win1, in1, fmaf(win0, in0, bni));                          \
    gi = fmaf(win2, in2, gi);                                                  \
    float nn = fmaf(-2.0f, frcp(1.0f + fexp2(fmaf(r, cnd.x, gi))), 1.0f);      \
    float omz = 1.0f - zz;                                                     \
    float zh  = zz * h;                                                        \
    float hn  = fmaf(omz, nn, zh);              /* (1-z)*n + z*h */            \
    if ((MODE) == 0)      h = hn;                                              \
    else if ((MODE) == 1) h = is_q0 ? hn : h;                                  \
    else                  h = is_q0 ? h : hn;                                  \
} while (0)

__global__ __launch_bounds__(64, 1)
void gru_pipe(const float* __restrict__ x,     // [B,T,3]
              const float* __restrict__ h0,    // [2,B,3]
              const float* __restrict__ Wih,   // [2,9,3]
              const float* __restrict__ Whh,   // [2,9,3]
              const float* __restrict__ bih,   // [2,9]
              const float* __restrict__ bhh,   // [2,9]
              const float* __restrict__ Wdec,  // [1,3]
              const float* __restrict__ bdec,  // [1]
              float* __restrict__ out)         // y[B*T] then h_out[2*B*3]
{
    const int lane  = threadIdx.x;           // 0..63, block = 1 wave
    const int g8    = lane & 7;              // position within 8-lane group
    const int layer = (g8 >> 2) & 1;         // quad parity = layer
    const int jj    = g8 & 3;
    const int j     = jj > 2 ? 2 : jj;       // clamped row (dummy lanes reuse j=2)
    const bool dummy = (jj == 3);
    const bool is_q0 = (layer == 0);
    const int b = (blockIdx.x * 64 + lane) >> 3;   // batch element

    // ---- per-lane weights, pre-scaled:
    //   r/z chains carry -log2(e); n chains carry 2*log2(e); dummy lanes zeroed
    const float zm = dummy ? 0.0f : 1.0f;
    const float sR = -LOG2E * zm, sN = 2.0f * LOG2E * zm;
    const float* Wi = Wih + layer * 27;
    const float* Wh = Whh + layer * 27;
    const float* bi = bih + layer * 9;
    const float* bh = bhh + layer * 9;

    v2f wirz0, wirz1, wirz2, whrz0, whrz1, whrz2, brz;
    wirz0.x = Wi[j*3+0]*sR;     wirz0.y = Wi[(3+j)*3+0]*sR;
    wirz1.x = Wi[j*3+1]*sR;     wirz1.y = Wi[(3+j)*3+1]*sR;
    wirz2.x = Wi[j*3+2]*sR;     wirz2.y = Wi[(3+j)*3+2]*sR;
    whrz0.x = Wh[j*3+0]*sR;     whrz0.y = Wh[(3+j)*3+0]*sR;
    whrz1.x = Wh[j*3+1]*sR;     whrz1.y = Wh[(3+j)*3+1]*sR;
    whrz2.x = Wh[j*3+2]*sR;     whrz2.y = Wh[(3+j)*3+2]*sR;
    brz.x   = (bi[j] + bh[j]) * sR;
    brz.y   = (bi[3+j] + bh[3+j]) * sR;

    const float wd0 = Wdec[0], wd1 = Wdec[1], wd2 = Wdec[2], bd = bdec[0];
    v2f wnd0, wnd1, wnd2, bnd;                     // {whn_k, wd_k}, {bnh, bd}
    wnd0.x = Wh[(6+j)*3+0]*sN;  wnd0.y = wd0;
    wnd1.x = Wh[(6+j)*3+1]*sN;  wnd1.y = wd1;
    wnd2.x = Wh[(6+j)*3+2]*sN;  wnd2.y = wd2;
    bnd.x  = bh[6+j]*sN;        bnd.y  = bd;

    const float win0 = Wi[(6+j)*3+0]*sN, win1 = Wi[(6+j)*3+1]*sN,
                win2 = Wi[(6+j)*3+2]*sN;
    const float bni  = bi[6+j]*sN;

    float h = dummy ? 0.0f : h0[layer * B * 3 + b * 3 + j];

    const float4* xb = reinterpret_cast<const float4*>(x + (size_t)b * T * 3);
    float* yo = out + (size_t)b * T;

    // double-buffered chunk registers: cu = chunk t, nx = chunk t+1
    float4 nx0 = xb[0], nx1 = xb[1], nx2 = xb[2];
    float4 cu0 = xb[3], cu1 = xb[4], cu2 = xb[5];
    float y0, y1, y2, y3, p2, p3;

    // ---- chunk 0 (prologue: freeze layer-1 h at i=0) ----
    {
        GRU_IT(1, nx0.x, nx0.y, nx0.z, y0);   // i=0
        GRU_IT(0, nx0.w, nx1.x, nx1.y, y1);   // i=1
        GRU_IT(0, nx1.z, nx1.w, nx2.x, y2);   // i=2 -> y(0)
        GRU_IT(0, nx2.y, nx2.z, nx2.w, y3);   // i=3 -> y(1)
        p2 = y2; p3 = y3;                     // carry y(0), y(1)
    }
    nx0 = xb[6]; nx1 = xb[7]; nx2 = xb[8];    // chunk 2
    // invariant entering loop (tc=1): cu = d(1), nx = d(2)

    #pragma unroll 1
    for (int tc = 1; tc <= 1021; tc += 2) {
        // entry: cu = d(tc), nx = d(tc+1)
        const float4* pfa = xb + (tc + 2) * 3;               // d(tc+2), always in-bounds
        float4 La0 = pfa[0], La1 = pfa[1], La2 = pfa[2];
        // ---- chunk tc (from cu) ----
        GRU_IT(0, cu0.x, cu0.y, cu0.z, y0);
        GRU_IT(0, cu0.w, cu1.x, cu1.y, y1);
        GRU_IT(0, cu1.z, cu1.w, cu2.x, y2);
        GRU_IT(0, cu2.y, cu2.z, cu2.w, y3);
        if (g8 == 7) {
            float4 q; q.x = p2; q.y = p3; q.z = y0; q.w = y1;
            *(float4*)(yo + 4 * tc - 4) = q;                 // y(4tc-4 .. 4tc-1)
        }
        p2 = y2; p3 = y3;
        const float4* pfb = xb + (((tc + 3) & 1023) * 3);    // d(tc+3), masked (tail wraps)
        float4 Lb0 = pfb[0], Lb1 = pfb[1], Lb2 = pfb[2];
        // ---- chunk tc+1 (from nx) ----
        GRU_IT(0, nx0.x, nx0.y, nx0.z, y0);
        GRU_IT(0, nx0.w, nx1.x, nx1.y, y1);
        GRU_IT(0, nx1.z, nx1.w, nx2.x, y2);
        GRU_IT(0, nx2.y, nx2.z, nx2.w, y3);
        if (g8 == 7) {
            float4 q; q.x = p2; q.y = p3; q.z = y0; q.w = y1;
            *(float4*)(yo + 4 * tc) = q;                     // y(4tc .. 4tc+3)
        }
        p2 = y2; p3 = y3;
        cu0 = La0; cu1 = La1; cu2 = La2;                     // d(tc+2)
        nx0 = Lb0; nx1 = Lb1; nx2 = Lb2;                     // d(tc+3)
    }
    // exit: cu = d(1023), nx = wrapped (unused)

    // ---- chunk 1023 ----
    GRU_IT(0, cu0.x, cu0.y, cu0.z, y0);
    GRU_IT(0, cu0.w, cu1.x, cu1.y, y1);
    GRU_IT(0, cu1.z, cu1.w, cu2.x, y2);
    GRU_IT(0, cu2.y, cu2.z, cu2.w, y3);
    if (g8 == 7) {
        float4 q; q.x = p2; q.y = p3; q.z = y0; q.w = y1;
        *(float4*)(yo + 4088) = q;                           // y(4088 .. 4091)
    }
    p2 = y2; p3 = y3;                                        // y(4092), y(4093)

    // ---- epilogue ----
    GRU_IT(2, 0.0f, 0.0f, 0.0f, y0);       // i=T: layer-1 finishes h1(T-1); y(T-2)
    {
        float hb0 = dppf<0x00>(h), hb1 = dppf<0x55>(h), hb2 = dppf<0xAA>(h);
        y1 = fmaf(wd2, hb2, fmaf(wd1, hb1, fmaf(wd0, hb0, bd)));   // y(T-1)
    }
    if (g8 == 7) {
        float4 q; q.x = p2; q.y = p3; q.z = y0; q.w = y1;
        *(float4*)(yo + 4092) = q;                           // y(4092 .. 4095)
    }

    // final hidden states
    if (!dummy) out[B * T + (layer * B + b) * 3 + j] = h;
}

extern "C" void kernel_launch(void* const* d_in, const int* in_sizes, int n_in,
                              void* d_out, int out_size, void* d_ws, size_t ws_size,
                              hipStream_t stream) {
    const float* x    = (const float*)d_in[0];
    const float* h0   = (const float*)d_in[1];
    const float* Wih  = (const float*)d_in[2];
    const float* Whh  = (const float*)d_in[3];
    const float* bih  = (const float*)d_in[4];
    const float* bhh  = (const float*)d_in[5];
    const float* Wdec = (const float*)d_in[6];
    const float* bdec = (const float*)d_in[7];
    float* out = (float*)d_out;

    gru_pipe<<<(B * 8) / 64, 64, 0, stream>>>(x, h0, Wih, Whh, bih, bhh,
                                              Wdec, bdec, out);
}